// Round 1
// baseline (404.933 us; speedup 1.0000x reference)
//
#include <hip/hip_runtime.h>
#include <math.h>

#define BB 512
#define SS 1024
#define KK 128
#define VV 512

static constexpr float INV_SCALE = 0.088388347648318447f; // 1/sqrt(128)

// ---------------- Attention kernel: fused query proj + masked softmax + PV ----
// One block per batch. 256 threads (4 waves).
__global__ __launch_bounds__(256) void attn_kernel(
    const float* __restrict__ keys,    // (B,S,K)
    const float* __restrict__ values,  // (B,S,V)
    const float* __restrict__ keyv,    // (B,K)
    const float* __restrict__ valv,    // (B,V)
    const float* __restrict__ hidden,  // (B,V)
    const int*   __restrict__ write_ptr, // (B)
    const int*   __restrict__ filled,    // (B)
    const float* __restrict__ Wq,      // (K,V)
    const float* __restrict__ bq,      // (K)
    float* __restrict__ retrieved)     // (B,V) scratch out
{
    __shared__ __align__(16) float hid[VV];
    __shared__ __align__(16) float qs[KK];
    __shared__ __align__(16) float qpart[2][KK];
    __shared__ __align__(16) float p[SS];
    __shared__ __align__(16) float red[256];

    const int b = blockIdx.x;
    const int t = threadIdx.x;
    const int wp = write_ptr[b];
    int f = filled[b] + 1; if (f > SS) f = SS;

    // stage hidden row into LDS
    {
        const float4* hg = (const float4*)(hidden + (size_t)b * VV);
        float4* hl = (float4*)hid;
        if (t < VV / 4) hl[t] = hg[t];
    }
    __syncthreads();

    // query = hidden[b] @ Wq.T + bq   (thread t: k = t&127, half = t>>7)
    {
        const int k = t & 127;
        const int half = t >> 7;
        const float4* w4 = (const float4*)(Wq + (size_t)k * VV + half * 256);
        const float4* h4 = (const float4*)(hid + half * 256);
        float acc = 0.f;
        #pragma unroll 8
        for (int v = 0; v < 64; ++v) {
            float4 a = w4[v], h = h4[v];
            acc += a.x * h.x + a.y * h.y + a.z * h.z + a.w * h.w;
        }
        qpart[half][k] = acc;
    }
    __syncthreads();
    if (t < KK) qs[t] = qpart[0][t] + qpart[1][t] + bq[t];
    __syncthreads();

    // pass 1: scores for s < f. 32 lanes per row, 8 rows per block-iter.
    const int wave = t >> 6;
    const int lane = t & 63;
    const int sub  = lane & 31;
    const int rsel = lane >> 5;
    const float4 q4 = ((const float4*)qs)[sub];
    for (int s0 = 0; s0 < f; s0 += 8) {
        const int s = s0 + wave * 2 + rsel;
        if (s < f) {
            const float* krow = (s == wp) ? (keyv + (size_t)b * KK)
                                          : (keys + ((size_t)b * SS + s) * KK);
            float4 kv = ((const float4*)krow)[sub];
            float partial = kv.x * q4.x + kv.y * q4.y + kv.z * q4.z + kv.w * q4.w;
            partial += __shfl_xor(partial, 16);
            partial += __shfl_xor(partial, 8);
            partial += __shfl_xor(partial, 4);
            partial += __shfl_xor(partial, 2);
            partial += __shfl_xor(partial, 1);
            if (sub == 0) p[s] = partial * INV_SCALE;
        }
    }
    __syncthreads();

    // softmax (unnormalized exp in p, fold 1/sum into final store)
    float lmax = -INFINITY;
    for (int i = t; i < f; i += 256) lmax = fmaxf(lmax, p[i]);
    red[t] = lmax; __syncthreads();
    for (int off = 128; off > 0; off >>= 1) {
        if (t < off) red[t] = fmaxf(red[t], red[t + off]);
        __syncthreads();
    }
    const float m = red[0];
    __syncthreads();
    float lsum = 0.f;
    for (int i = t; i < f; i += 256) {
        float e = __expf(p[i] - m);
        p[i] = e;
        lsum += e;
    }
    red[t] = lsum; __syncthreads();
    for (int off = 128; off > 0; off >>= 1) {
        if (t < off) red[t] += red[t + off];
        __syncthreads();
    }
    const float inv = 1.f / red[0];

    // pass 2: retrieved[b,:] = (sum_s p[s] * values_w[b,s,:]) * inv
    {
        float2 acc = make_float2(0.f, 0.f);
        const float2* vb = (const float2*)(values + (size_t)b * SS * VV);
        const float2* vw = (const float2*)(valv + (size_t)b * VV);
        for (int s = 0; s < f; ++s) {
            const float ps = p[s];
            const float2* vr = (s == wp) ? vw : (vb + (size_t)s * (VV / 2));
            float2 x = vr[t];
            acc.x += ps * x.x;
            acc.y += ps * x.y;
        }
        float2 r;
        r.x = acc.x * inv;
        r.y = acc.y * inv;
        ((float2*)(retrieved + (size_t)b * VV))[t] = r;
    }
}

// ---------------- Fused gate MLP ---------------------------------------------
// g    = silu([hidden, retrieved] @ Wg1.T + bg1)
// gate = sigmoid(g @ Wg2.T + bg2)
// out  = (hidden + gate * retrieved) @ Wo.T + bo
// TB batches per block; 256 threads; each thread owns j = {t, t+256}.
#define TB 4
__global__ __launch_bounds__(256) void mlp_kernel(
    const float* __restrict__ hidden,
    const float* __restrict__ retrieved,
    const float* __restrict__ Wg1, const float* __restrict__ bg1,  // (V,2V),(V)
    const float* __restrict__ Wg2, const float* __restrict__ bg2,  // (V,V),(V)
    const float* __restrict__ Wo,  const float* __restrict__ bo,   // (V,V),(V)
    float* __restrict__ out)
{
    __shared__ __align__(16) float hcat[TB][2 * VV];  // 16 KB
    __shared__ __align__(16) float gbuf[TB][VV];      // 8 KB
    __shared__ __align__(16) float xbuf[TB][VV];      // 8 KB

    const int t = threadIdx.x;
    const int b0 = blockIdx.x * TB;

    // stage hcat = [hidden | retrieved]
    {
        float4* hc4 = (float4*)hcat;
        const int row4 = 2 * VV / 4;  // 256 float4 per row
        for (int i = t; i < TB * row4; i += 256) {
            const int b = i / row4;
            const int v4 = i % row4;
            float4 val;
            if (v4 < VV / 4)
                val = ((const float4*)(hidden + (size_t)(b0 + b) * VV))[v4];
            else
                val = ((const float4*)(retrieved + (size_t)(b0 + b) * VV))[v4 - VV / 4];
            hc4[i] = val;
        }
    }
    __syncthreads();

    // layer 1
    for (int jj = 0; jj < 2; ++jj) {
        const int j = t + jj * 256;
        const float4* w = (const float4*)(Wg1 + (size_t)j * (2 * VV));
        float acc[TB];
        #pragma unroll
        for (int b = 0; b < TB; ++b) acc[b] = bg1[j];
        for (int v4 = 0; v4 < 2 * VV / 4; ++v4) {
            const float4 wv = w[v4];
            #pragma unroll
            for (int b = 0; b < TB; ++b) {
                const float4 h = ((const float4*)hcat[b])[v4];
                acc[b] += wv.x * h.x + wv.y * h.y + wv.z * h.z + wv.w * h.w;
            }
        }
        #pragma unroll
        for (int b = 0; b < TB; ++b) {
            const float a = acc[b];
            gbuf[b][j] = a / (1.f + __expf(-a));  // silu
        }
    }
    __syncthreads();

    // layer 2 + gating
    for (int jj = 0; jj < 2; ++jj) {
        const int j = t + jj * 256;
        const float4* w = (const float4*)(Wg2 + (size_t)j * VV);
        float acc[TB];
        #pragma unroll
        for (int b = 0; b < TB; ++b) acc[b] = bg2[j];
        for (int v4 = 0; v4 < VV / 4; ++v4) {
            const float4 wv = w[v4];
            #pragma unroll
            for (int b = 0; b < TB; ++b) {
                const float4 h = ((const float4*)gbuf[b])[v4];
                acc[b] += wv.x * h.x + wv.y * h.y + wv.z * h.z + wv.w * h.w;
            }
        }
        #pragma unroll
        for (int b = 0; b < TB; ++b) {
            const float gate = 1.f / (1.f + __expf(-acc[b]));
            // x = hidden + gate * retrieved  (both still in hcat)
            xbuf[b][j] = hcat[b][j] + gate * hcat[b][VV + j];
        }
    }
    __syncthreads();

    // layer 3
    for (int jj = 0; jj < 2; ++jj) {
        const int j = t + jj * 256;
        const float4* w = (const float4*)(Wo + (size_t)j * VV);
        float acc[TB];
        #pragma unroll
        for (int b = 0; b < TB; ++b) acc[b] = bo[j];
        for (int v4 = 0; v4 < VV / 4; ++v4) {
            const float4 wv = w[v4];
            #pragma unroll
            for (int b = 0; b < TB; ++b) {
                const float4 h = ((const float4*)xbuf[b])[v4];
                acc[b] += wv.x * h.x + wv.y * h.y + wv.z * h.z + wv.w * h.w;
            }
        }
        #pragma unroll
        for (int b = 0; b < TB; ++b) {
            out[(size_t)(b0 + b) * VV + j] = acc[b];
        }
    }
}

extern "C" void kernel_launch(void* const* d_in, const int* in_sizes, int n_in,
                              void* d_out, int out_size, void* d_ws, size_t ws_size,
                              hipStream_t stream) {
    const float* keys    = (const float*)d_in[0];
    const float* values  = (const float*)d_in[1];
    const float* keyv    = (const float*)d_in[2];
    const float* valv    = (const float*)d_in[3];
    const float* hidden  = (const float*)d_in[4];
    const int*   wptr    = (const int*)d_in[5];
    const int*   filled  = (const int*)d_in[6];
    const float* Wq  = (const float*)d_in[7];
    const float* bq  = (const float*)d_in[8];
    const float* Wg1 = (const float*)d_in[9];
    const float* bg1 = (const float*)d_in[10];
    const float* Wg2 = (const float*)d_in[11];
    const float* bg2 = (const float*)d_in[12];
    const float* Wo  = (const float*)d_in[13];
    const float* bo  = (const float*)d_in[14];

    float* out = (float*)d_out;
    float* retrieved = (float*)d_ws;  // B*V floats = 1 MB

    attn_kernel<<<BB, 256, 0, stream>>>(keys, values, keyv, valv, hidden,
                                        wptr, filled, Wq, bq, retrieved);
    mlp_kernel<<<BB / TB, 256, 0, stream>>>(hidden, retrieved,
                                            Wg1, bg1, Wg2, bg2, Wo, bo, out);
}

// Round 2
// 376.848 us; speedup vs baseline: 1.0745x; 1.0745x over previous
//
#include <hip/hip_runtime.h>
#include <math.h>

#define BB 512
#define SS 1024
#define KK 128
#define VV 512

static constexpr float INV_SCALE = 0.088388347648318447f; // 1/sqrt(128)

// ---------------- Attention kernel: fused query proj + masked softmax + PV ----
// One block per batch. 256 threads (4 waves).
__global__ __launch_bounds__(256) void attn_kernel(
    const float* __restrict__ keys,    // (B,S,K)
    const float* __restrict__ values,  // (B,S,V)
    const float* __restrict__ keyv,    // (B,K)
    const float* __restrict__ valv,    // (B,V)
    const float* __restrict__ hidden,  // (B,V)
    const int*   __restrict__ write_ptr, // (B)
    const int*   __restrict__ filled,    // (B)
    const float* __restrict__ Wq,      // (K,V)
    const float* __restrict__ bq,      // (K)
    float* __restrict__ retrieved)     // (B,V) scratch out
{
    __shared__ __align__(16) float hid[VV];
    __shared__ __align__(16) float qs[KK];
    __shared__ __align__(16) float qpart[2][KK];
    __shared__ __align__(16) float p[SS];
    __shared__ __align__(16) float red[256];
    __shared__ __align__(16) float4 pv1[VV / 4];

    const int b = blockIdx.x;
    const int t = threadIdx.x;
    const int wp = write_ptr[b];
    int f = filled[b] + 1; if (f > SS) f = SS;

    // stage hidden row into LDS
    {
        const float4* hg = (const float4*)(hidden + (size_t)b * VV);
        float4* hl = (float4*)hid;
        if (t < VV / 4) hl[t] = hg[t];
    }
    __syncthreads();

    // query = hidden[b] @ Wq.T + bq   (thread t: k = t&127, half = t>>7)
    {
        const int k = t & 127;
        const int half = t >> 7;
        const float4* w4 = (const float4*)(Wq + (size_t)k * VV + half * 256);
        const float4* h4 = (const float4*)(hid + half * 256);
        float acc = 0.f;
        #pragma unroll 8
        for (int v = 0; v < 64; ++v) {
            float4 a = w4[v], h = h4[v];
            acc += a.x * h.x + a.y * h.y + a.z * h.z + a.w * h.w;
        }
        qpart[half][k] = acc;
    }
    __syncthreads();
    if (t < KK) qs[t] = qpart[0][t] + qpart[1][t] + bq[t];
    __syncthreads();

    // pass 1: scores for s < f. 32 lanes per row (float4), 8 rows per wave-set,
    // manually unrolled x4 -> 32 rows per iteration, 4 loads in flight per lane.
    const int wave = t >> 6;
    const int lane = t & 63;
    const int sub  = lane & 31;
    const int rsel = lane >> 5;
    const int srow = wave * 2 + rsel;             // 0..7
    const float4 q4 = ((const float4*)qs)[sub];
    const float* kb = keys + (size_t)b * SS * KK;
    const float* kw = keyv + (size_t)b * KK;
    for (int s0 = 0; s0 < f; s0 += 32) {
        float4 kv[4];
        int sv[4];
        #pragma unroll
        for (int u = 0; u < 4; ++u) {
            const int s = s0 + u * 8 + srow;
            sv[u] = s;
            if (s < f) {
                const float* krow = (s == wp) ? kw : (kb + (size_t)s * KK);
                kv[u] = ((const float4*)krow)[sub];
            }
        }
        #pragma unroll
        for (int u = 0; u < 4; ++u) {
            if (sv[u] < f) {
                float partial = kv[u].x * q4.x + kv[u].y * q4.y
                              + kv[u].z * q4.z + kv[u].w * q4.w;
                partial += __shfl_xor(partial, 16);
                partial += __shfl_xor(partial, 8);
                partial += __shfl_xor(partial, 4);
                partial += __shfl_xor(partial, 2);
                partial += __shfl_xor(partial, 1);
                if (sub == 0) p[sv[u]] = partial * INV_SCALE;
            }
        }
    }
    __syncthreads();

    // softmax (unnormalized exp in p, fold 1/sum into final store)
    float lmax = -INFINITY;
    for (int i = t; i < f; i += 256) lmax = fmaxf(lmax, p[i]);
    red[t] = lmax; __syncthreads();
    for (int off = 128; off > 0; off >>= 1) {
        if (t < off) red[t] = fmaxf(red[t], red[t + off]);
        __syncthreads();
    }
    const float m = red[0];
    __syncthreads();
    float lsum = 0.f;
    for (int i = t; i < f; i += 256) {
        float e = __expf(p[i] - m);
        p[i] = e;
        lsum += e;
    }
    red[t] = lsum; __syncthreads();
    for (int off = 128; off > 0; off >>= 1) {
        if (t < off) red[t] += red[t + off];
        __syncthreads();
    }
    const float inv = 1.f / red[0];
    __syncthreads();

    // pass 2: retrieved[b,:] = (sum_s p[s] * values_w[b,s,:]) * inv
    // thread t: float4 column group col4 = t&127; s-stream shalf = t>>7 (s%2).
    // unroll x4 -> 4 independent 16B loads in flight per thread.
    {
        const int col4 = t & 127;
        const int shalf = t >> 7;
        const float4* vb = (const float4*)(values + (size_t)b * SS * VV);
        const float4* vwp = (const float4*)(valv + (size_t)b * VV);
        float4 acc = make_float4(0.f, 0.f, 0.f, 0.f);
        for (int s0 = shalf; s0 < f; s0 += 8) {
            float4 v[4];
            float ps[4];
            int sv[4];
            #pragma unroll
            for (int u = 0; u < 4; ++u) {
                const int s = s0 + 2 * u;
                sv[u] = s;
                if (s < f) {
                    const float4* vr = (s == wp) ? vwp : (vb + (size_t)s * (VV / 4));
                    v[u] = vr[col4];
                    ps[u] = p[s];
                }
            }
            #pragma unroll
            for (int u = 0; u < 4; ++u) {
                if (sv[u] < f) {
                    acc.x += ps[u] * v[u].x;
                    acc.y += ps[u] * v[u].y;
                    acc.z += ps[u] * v[u].z;
                    acc.w += ps[u] * v[u].w;
                }
            }
        }
        if (shalf == 1) pv1[col4] = acc;
        __syncthreads();
        if (shalf == 0) {
            const float4 o = pv1[col4];
            float4 r;
            r.x = (acc.x + o.x) * inv;
            r.y = (acc.y + o.y) * inv;
            r.z = (acc.z + o.z) * inv;
            r.w = (acc.w + o.w) * inv;
            ((float4*)(retrieved + (size_t)b * VV))[col4] = r;
        }
    }
}

// ---------------- Fused gate MLP ---------------------------------------------
// g    = silu([hidden, retrieved] @ Wg1.T + bg1)
// gate = sigmoid(g @ Wg2.T + bg2)
// out  = (hidden + gate * retrieved) @ Wo.T + bo
// TB batches per block; 256 threads; each thread owns j = {t, t+256}.
#define TB 2
__global__ __launch_bounds__(256) void mlp_kernel(
    const float* __restrict__ hidden,
    const float* __restrict__ retrieved,
    const float* __restrict__ Wg1, const float* __restrict__ bg1,  // (V,2V),(V)
    const float* __restrict__ Wg2, const float* __restrict__ bg2,  // (V,V),(V)
    const float* __restrict__ Wo,  const float* __restrict__ bo,   // (V,V),(V)
    float* __restrict__ out)
{
    __shared__ __align__(16) float hcat[TB][2 * VV];
    __shared__ __align__(16) float gbuf[TB][VV];
    __shared__ __align__(16) float xbuf[TB][VV];

    const int t = threadIdx.x;
    const int b0 = blockIdx.x * TB;

    // stage hcat = [hidden | retrieved]
    {
        float4* hc4 = (float4*)hcat;
        const int row4 = 2 * VV / 4;  // 256 float4 per row
        for (int i = t; i < TB * row4; i += 256) {
            const int b = i / row4;
            const int v4 = i % row4;
            float4 val;
            if (v4 < VV / 4)
                val = ((const float4*)(hidden + (size_t)(b0 + b) * VV))[v4];
            else
                val = ((const float4*)(retrieved + (size_t)(b0 + b) * VV))[v4 - VV / 4];
            hc4[i] = val;
        }
    }
    __syncthreads();

    // layer 1
    for (int jj = 0; jj < 2; ++jj) {
        const int j = t + jj * 256;
        const float4* w = (const float4*)(Wg1 + (size_t)j * (2 * VV));
        float acc[TB];
        #pragma unroll
        for (int b = 0; b < TB; ++b) acc[b] = bg1[j];
        for (int v4 = 0; v4 < 2 * VV / 4; ++v4) {
            const float4 wv = w[v4];
            #pragma unroll
            for (int b = 0; b < TB; ++b) {
                const float4 h = ((const float4*)hcat[b])[v4];
                acc[b] += wv.x * h.x + wv.y * h.y + wv.z * h.z + wv.w * h.w;
            }
        }
        #pragma unroll
        for (int b = 0; b < TB; ++b) {
            const float a = acc[b];
            gbuf[b][j] = a / (1.f + __expf(-a));  // silu
        }
    }
    __syncthreads();

    // layer 2 + gating
    for (int jj = 0; jj < 2; ++jj) {
        const int j = t + jj * 256;
        const float4* w = (const float4*)(Wg2 + (size_t)j * VV);
        float acc[TB];
        #pragma unroll
        for (int b = 0; b < TB; ++b) acc[b] = bg2[j];
        for (int v4 = 0; v4 < VV / 4; ++v4) {
            const float4 wv = w[v4];
            #pragma unroll
            for (int b = 0; b < TB; ++b) {
                const float4 h = ((const float4*)gbuf[b])[v4];
                acc[b] += wv.x * h.x + wv.y * h.y + wv.z * h.z + wv.w * h.w;
            }
        }
        #pragma unroll
        for (int b = 0; b < TB; ++b) {
            const float gate = 1.f / (1.f + __expf(-acc[b]));
            xbuf[b][j] = hcat[b][j] + gate * hcat[b][VV + j];
        }
    }
    __syncthreads();

    // layer 3
    for (int jj = 0; jj < 2; ++jj) {
        const int j = t + jj * 256;
        const float4* w = (const float4*)(Wo + (size_t)j * VV);
        float acc[TB];
        #pragma unroll
        for (int b = 0; b < TB; ++b) acc[b] = bo[j];
        for (int v4 = 0; v4 < VV / 4; ++v4) {
            const float4 wv = w[v4];
            #pragma unroll
            for (int b = 0; b < TB; ++b) {
                const float4 h = ((const float4*)xbuf[b])[v4];
                acc[b] += wv.x * h.x + wv.y * h.y + wv.z * h.z + wv.w * h.w;
            }
        }
        #pragma unroll
        for (int b = 0; b < TB; ++b) {
            out[(size_t)(b0 + b) * VV + j] = acc[b];
        }
    }
}

extern "C" void kernel_launch(void* const* d_in, const int* in_sizes, int n_in,
                              void* d_out, int out_size, void* d_ws, size_t ws_size,
                              hipStream_t stream) {
    const float* keys    = (const float*)d_in[0];
    const float* values  = (const float*)d_in[1];
    const float* keyv    = (const float*)d_in[2];
    const float* valv    = (const float*)d_in[3];
    const float* hidden  = (const float*)d_in[4];
    const int*   wptr    = (const int*)d_in[5];
    const int*   filled  = (const int*)d_in[6];
    const float* Wq  = (const float*)d_in[7];
    const float* bq  = (const float*)d_in[8];
    const float* Wg1 = (const float*)d_in[9];
    const float* bg1 = (const float*)d_in[10];
    const float* Wg2 = (const float*)d_in[11];
    const float* bg2 = (const float*)d_in[12];
    const float* Wo  = (const float*)d_in[13];
    const float* bo  = (const float*)d_in[14];

    float* out = (float*)d_out;
    float* retrieved = (float*)d_ws;  // B*V floats = 1 MB

    attn_kernel<<<BB, 256, 0, stream>>>(keys, values, keyv, valv, hidden,
                                        wptr, filled, Wq, bq, retrieved);
    mlp_kernel<<<BB / TB, 256, 0, stream>>>(hidden, retrieved,
                                            Wg1, bg1, Wg2, bg2, Wo, bo, out);
}

// Round 3
// 312.525 us; speedup vs baseline: 1.2957x; 1.2058x over previous
//
#include <hip/hip_runtime.h>
#include <math.h>

#define BB 512
#define SS 1024
#define KK 128
#define VV 512
#define NT 512

static constexpr float INV_SCALE = 0.088388347648318447f; // 1/sqrt(128)

// ---------------- Attention kernel: fused query proj + masked softmax + PV ----
// One block per batch. 512 threads (8 waves).
__global__ __launch_bounds__(512) void attn_kernel(
    const float* __restrict__ keys,    // (B,S,K)
    const float* __restrict__ values,  // (B,S,V)
    const float* __restrict__ keyv,    // (B,K)
    const float* __restrict__ valv,    // (B,V)
    const float* __restrict__ hidden,  // (B,V)
    const int*   __restrict__ write_ptr, // (B)
    const int*   __restrict__ filled,    // (B)
    const float* __restrict__ Wq,      // (K,V)
    const float* __restrict__ bq,      // (K)
    float* __restrict__ retrieved)     // (B,V) scratch out
{
    __shared__ __align__(16) float hid[VV];
    __shared__ __align__(16) float qs[KK];
    __shared__ __align__(16) float qpart[4][KK];
    __shared__ __align__(16) float p[SS];
    __shared__ __align__(16) float red[8];
    __shared__ __align__(16) float4 pvp[3][VV / 4];

    const int b = blockIdx.x;
    const int t = threadIdx.x;
    const int wave = t >> 6;
    const int lane = t & 63;
    const int wp = write_ptr[b];
    int f = filled[b] + 1; if (f > SS) f = SS;

    // stage hidden row into LDS
    if (t < VV / 4)
        ((float4*)hid)[t] = ((const float4*)(hidden + (size_t)b * VV))[t];
    __syncthreads();

    // query = hidden[b] @ Wq.T + bq   (thread t: k = t&127, quarter = t>>7)
    {
        const int k = t & 127;
        const int q = t >> 7;
        const float4* w4 = (const float4*)(Wq + (size_t)k * VV + q * 128);
        const float4* h4 = (const float4*)(hid + q * 128);
        float acc = 0.f;
        #pragma unroll
        for (int v = 0; v < 32; ++v) {
            float4 a = w4[v], h = h4[v];
            acc += a.x * h.x + a.y * h.y + a.z * h.z + a.w * h.w;
        }
        qpart[q][k] = acc;
    }
    __syncthreads();
    if (t < KK)
        qs[t] = qpart[0][t] + qpart[1][t] + qpart[2][t] + qpart[3][t] + bq[t];
    __syncthreads();

    // ---- pass 1: scores. 32 lanes per row (float4 each), 16 rows per block
    // sweep, unroll x4 -> 64 rows/iter, 4 loads in flight/lane, NO guards.
    const int sub  = lane & 31;
    const int rsel = lane >> 5;
    const int srow = wave * 2 + rsel;             // 0..15
    const float4 q4 = ((const float4*)qs)[sub];
    const float* kb = keys + (size_t)b * SS * KK;
    const float* kw = keyv + (size_t)b * KK;
    const int fmain1 = f & ~63;
    for (int s0 = 0; s0 < fmain1; s0 += 64) {
        float4 kv[4];
        #pragma unroll
        for (int u = 0; u < 4; ++u) {
            const int s = s0 + u * 16 + srow;
            const float* kr = (s == wp) ? kw : (kb + (size_t)s * KK);
            kv[u] = ((const float4*)kr)[sub];
        }
        #pragma unroll
        for (int u = 0; u < 4; ++u) {
            float partial = kv[u].x * q4.x + kv[u].y * q4.y
                          + kv[u].z * q4.z + kv[u].w * q4.w;
            partial += __shfl_xor(partial, 16);
            partial += __shfl_xor(partial, 8);
            partial += __shfl_xor(partial, 4);
            partial += __shfl_xor(partial, 2);
            partial += __shfl_xor(partial, 1);
            if (sub == 0) p[s0 + u * 16 + srow] = partial * INV_SCALE;
        }
    }
    for (int s = fmain1 + srow; s < f; s += 16) {
        const float* kr = (s == wp) ? kw : (kb + (size_t)s * KK);
        float4 kv = ((const float4*)kr)[sub];
        float partial = kv.x * q4.x + kv.y * q4.y + kv.z * q4.z + kv.w * q4.w;
        partial += __shfl_xor(partial, 16);
        partial += __shfl_xor(partial, 8);
        partial += __shfl_xor(partial, 4);
        partial += __shfl_xor(partial, 2);
        partial += __shfl_xor(partial, 1);
        if (sub == 0) p[s] = partial * INV_SCALE;
    }
    __syncthreads();

    // ---- softmax: wave shfl reduce + 8-entry LDS combine.
    float lmax = -INFINITY;
    for (int i = t; i < f; i += NT) lmax = fmaxf(lmax, p[i]);
    lmax = fmaxf(lmax, __shfl_xor(lmax, 32));
    lmax = fmaxf(lmax, __shfl_xor(lmax, 16));
    lmax = fmaxf(lmax, __shfl_xor(lmax, 8));
    lmax = fmaxf(lmax, __shfl_xor(lmax, 4));
    lmax = fmaxf(lmax, __shfl_xor(lmax, 2));
    lmax = fmaxf(lmax, __shfl_xor(lmax, 1));
    if (lane == 0) red[wave] = lmax;
    __syncthreads();
    const float m = fmaxf(fmaxf(fmaxf(red[0], red[1]), fmaxf(red[2], red[3])),
                          fmaxf(fmaxf(red[4], red[5]), fmaxf(red[6], red[7])));
    float lsum = 0.f;
    for (int i = t; i < f; i += NT) {
        float e = __expf(p[i] - m);
        p[i] = e;
        lsum += e;
    }
    lsum += __shfl_xor(lsum, 32);
    lsum += __shfl_xor(lsum, 16);
    lsum += __shfl_xor(lsum, 8);
    lsum += __shfl_xor(lsum, 4);
    lsum += __shfl_xor(lsum, 2);
    lsum += __shfl_xor(lsum, 1);
    __syncthreads();  // all reads of red(max) + writes of p done
    if (lane == 0) red[wave] = lsum;
    __syncthreads();
    const float inv = 1.f / (red[0] + red[1] + red[2] + red[3]
                           + red[4] + red[5] + red[6] + red[7]);

    // ---- pass 2: retrieved = (sum_s p[s] * values_w[b,s,:]) * inv
    // col4 = t&127 (float4 column), stream = t>>7 handles s%4==stream.
    // unroll x8, NO guards in main loop -> 8 x 16B loads in flight/thread.
    {
        const int col4 = t & 127;
        const int stream = t >> 7;
        const float4* vb = (const float4*)(values + (size_t)b * SS * VV);
        const float4* vwp = (const float4*)(valv + (size_t)b * VV);
        float4 acc = make_float4(0.f, 0.f, 0.f, 0.f);
        const int fmain = f & ~31;
        for (int s0 = 0; s0 < fmain; s0 += 32) {
            float4 v[8];
            float ps[8];
            #pragma unroll
            for (int u = 0; u < 8; ++u) {
                const int s = s0 + u * 4 + stream;
                const float4* vr = (s == wp) ? vwp : (vb + (size_t)s * (VV / 4));
                v[u] = vr[col4];
                ps[u] = p[s];
            }
            #pragma unroll
            for (int u = 0; u < 8; ++u) {
                acc.x += ps[u] * v[u].x;
                acc.y += ps[u] * v[u].y;
                acc.z += ps[u] * v[u].z;
                acc.w += ps[u] * v[u].w;
            }
        }
        for (int s = fmain + stream; s < f; s += 4) {
            const float4* vr = (s == wp) ? vwp : (vb + (size_t)s * (VV / 4));
            const float4 v = vr[col4];
            const float ps = p[s];
            acc.x += ps * v.x;
            acc.y += ps * v.y;
            acc.z += ps * v.z;
            acc.w += ps * v.w;
        }
        if (stream > 0) pvp[stream - 1][col4] = acc;
        __syncthreads();
        if (stream == 0) {
            const float4 p1 = pvp[0][col4];
            const float4 p2 = pvp[1][col4];
            const float4 p3 = pvp[2][col4];
            float4 r;
            r.x = (acc.x + p1.x + p2.x + p3.x) * inv;
            r.y = (acc.y + p1.y + p2.y + p3.y) * inv;
            r.z = (acc.z + p1.z + p2.z + p3.z) * inv;
            r.w = (acc.w + p1.w + p2.w + p3.w) * inv;
            ((float4*)(retrieved + (size_t)b * VV))[col4] = r;
        }
    }
}

// ---------------- Fused gate MLP ---------------------------------------------
#define TB 2
__global__ __launch_bounds__(256) void mlp_kernel(
    const float* __restrict__ hidden,
    const float* __restrict__ retrieved,
    const float* __restrict__ Wg1, const float* __restrict__ bg1,  // (V,2V),(V)
    const float* __restrict__ Wg2, const float* __restrict__ bg2,  // (V,V),(V)
    const float* __restrict__ Wo,  const float* __restrict__ bo,   // (V,V),(V)
    float* __restrict__ out)
{
    __shared__ __align__(16) float hcat[TB][2 * VV];
    __shared__ __align__(16) float gbuf[TB][VV];
    __shared__ __align__(16) float xbuf[TB][VV];

    const int t = threadIdx.x;
    const int b0 = blockIdx.x * TB;

    {
        float4* hc4 = (float4*)hcat;
        const int row4 = 2 * VV / 4;  // 256 float4 per row
        for (int i = t; i < TB * row4; i += 256) {
            const int b = i / row4;
            const int v4 = i % row4;
            float4 val;
            if (v4 < VV / 4)
                val = ((const float4*)(hidden + (size_t)(b0 + b) * VV))[v4];
            else
                val = ((const float4*)(retrieved + (size_t)(b0 + b) * VV))[v4 - VV / 4];
            hc4[i] = val;
        }
    }
    __syncthreads();

    // layer 1
    for (int jj = 0; jj < 2; ++jj) {
        const int j = t + jj * 256;
        const float4* w = (const float4*)(Wg1 + (size_t)j * (2 * VV));
        float acc[TB];
        #pragma unroll
        for (int b = 0; b < TB; ++b) acc[b] = bg1[j];
        for (int v4 = 0; v4 < 2 * VV / 4; ++v4) {
            const float4 wv = w[v4];
            #pragma unroll
            for (int b = 0; b < TB; ++b) {
                const float4 h = ((const float4*)hcat[b])[v4];
                acc[b] += wv.x * h.x + wv.y * h.y + wv.z * h.z + wv.w * h.w;
            }
        }
        #pragma unroll
        for (int b = 0; b < TB; ++b) {
            const float a = acc[b];
            gbuf[b][j] = a / (1.f + __expf(-a));  // silu
        }
    }
    __syncthreads();

    // layer 2 + gating
    for (int jj = 0; jj < 2; ++jj) {
        const int j = t + jj * 256;
        const float4* w = (const float4*)(Wg2 + (size_t)j * VV);
        float acc[TB];
        #pragma unroll
        for (int b = 0; b < TB; ++b) acc[b] = bg2[j];
        for (int v4 = 0; v4 < VV / 4; ++v4) {
            const float4 wv = w[v4];
            #pragma unroll
            for (int b = 0; b < TB; ++b) {
                const float4 h = ((const float4*)gbuf[b])[v4];
                acc[b] += wv.x * h.x + wv.y * h.y + wv.z * h.z + wv.w * h.w;
            }
        }
        #pragma unroll
        for (int b = 0; b < TB; ++b) {
            const float gate = 1.f / (1.f + __expf(-acc[b]));
            xbuf[b][j] = hcat[b][j] + gate * hcat[b][VV + j];
        }
    }
    __syncthreads();

    // layer 3
    for (int jj = 0; jj < 2; ++jj) {
        const int j = t + jj * 256;
        const float4* w = (const float4*)(Wo + (size_t)j * VV);
        float acc[TB];
        #pragma unroll
        for (int b = 0; b < TB; ++b) acc[b] = bo[j];
        for (int v4 = 0; v4 < VV / 4; ++v4) {
            const float4 wv = w[v4];
            #pragma unroll
            for (int b = 0; b < TB; ++b) {
                const float4 h = ((const float4*)xbuf[b])[v4];
                acc[b] += wv.x * h.x + wv.y * h.y + wv.z * h.z + wv.w * h.w;
            }
        }
        #pragma unroll
        for (int b = 0; b < TB; ++b) {
            out[(size_t)(b0 + b) * VV + j] = acc[b];
        }
    }
}

extern "C" void kernel_launch(void* const* d_in, const int* in_sizes, int n_in,
                              void* d_out, int out_size, void* d_ws, size_t ws_size,
                              hipStream_t stream) {
    const float* keys    = (const float*)d_in[0];
    const float* values  = (const float*)d_in[1];
    const float* keyv    = (const float*)d_in[2];
    const float* valv    = (const float*)d_in[3];
    const float* hidden  = (const float*)d_in[4];
    const int*   wptr    = (const int*)d_in[5];
    const int*   filled  = (const int*)d_in[6];
    const float* Wq  = (const float*)d_in[7];
    const float* bq  = (const float*)d_in[8];
    const float* Wg1 = (const float*)d_in[9];
    const float* bg1 = (const float*)d_in[10];
    const float* Wg2 = (const float*)d_in[11];
    const float* bg2 = (const float*)d_in[12];
    const float* Wo  = (const float*)d_in[13];
    const float* bo  = (const float*)d_in[14];

    float* out = (float*)d_out;
    float* retrieved = (float*)d_ws;  // B*V floats = 1 MB

    attn_kernel<<<BB, NT, 0, stream>>>(keys, values, keyv, valv, hidden,
                                       wptr, filled, Wq, bq, retrieved);
    mlp_kernel<<<BB / TB, 256, 0, stream>>>(hidden, retrieved,
                                            Wg1, bg1, Wg2, bg2, Wo, bo, out);
}